// Round 2
// baseline (394.272 us; speedup 1.0000x reference)
//
#include <hip/hip_runtime.h>

#define HW   6144
#define WID  96
#define HEI  64
#define CH   128
#define IC   243
#define OC   128

// ws float offsets
#define OF1T   0u
#define OF2L0  1572864u
#define OF2L1  3145728u
#define OF2L2  3538944u
#define OWT    3637248u
#define OFEAT  3668352u
#define OYPRE  6654336u
#define OSTAT  8227200u
// total floats = 8227232 -> 32.9 MB

__global__ void k_transpose(const float* __restrict__ f1, const float* __restrict__ f2,
                            float* __restrict__ ws) {
    int tid = blockIdx.x * 256 + threadIdx.x;           // 0..1572863
    const float* src = blockIdx.y ? f2 : f1;
    float* dst = ws + (blockIdx.y ? OF2L0 : OF1T);
    int c = tid & 127;
    int rest = tid >> 7;          // b*HW + pix
    int b = rest / HW;
    int pix = rest - b * HW;
    dst[tid] = src[((size_t)(b * CH + c)) * HW + pix];
}

__global__ void k_wt(const float* __restrict__ w, float* __restrict__ ws) {
    int tid = blockIdx.x * 256 + threadIdx.x;
    if (tid < IC * OC) {
        int k = tid >> 7, o = tid & 127;
        ws[OWT + tid] = w[o * IC + k];
    }
}

__global__ void k_pool(const float* __restrict__ src, float* __restrict__ dst, int Ho, int Wo) {
    int tid = blockIdx.x * 256 + threadIdx.x;
    int c = tid & 127;
    int rest = tid >> 7;
    int x = rest % Wo; rest /= Wo;
    int y = rest % Ho;
    int b = rest / Ho;
    int Wi = Wo * 2;
    const float* s = src + ((size_t)((b * (Ho * 2) + 2 * y) * Wi + 2 * x)) * CH + c;
    float v = s[0] + s[CH] + s[(size_t)Wi * CH] + s[(size_t)Wi * CH + CH];
    dst[tid] = 0.25f * v;
}

__launch_bounds__(256)
__global__ void k_corr(const float* __restrict__ txy, float* __restrict__ ws) {
    const int tid = threadIdx.x;
    const int pix0 = blockIdx.x * 16;       // global pixel (b*HW + pb)
    const int b = pix0 / HW;
    const int pb0 = pix0 - b * HW;

    __shared__ float sf1[16 * 128];
    __shared__ float sG[16 * 300];
    __shared__ float sLev[16 * 12];         // per pixel, per level: X0,Y0,fx,fy

    const float* f1t = ws + OF1T + ((size_t)pix0) * 128;
    for (int i = tid; i < 16 * 128; i += 256) sf1[i] = f1t[i];

    if (tid < 48) {
        int p = tid / 3, lev = tid - 3 * p;
        float tx = txy[(b * 2 + 0) * HW + pb0 + p];
        float ty = txy[(b * 2 + 1) * HW + pb0 + p];
        float inv = (lev == 0) ? 1.f : ((lev == 1) ? 0.5f : 0.25f);
        float xs = tx * inv, ys = ty * inv;
        float X0 = floorf(xs), Y0 = floorf(ys);
        sLev[p * 12 + lev * 4 + 0] = X0;
        sLev[p * 12 + lev * 4 + 1] = Y0;
        sLev[p * 12 + lev * 4 + 2] = xs - X0;
        sLev[p * 12 + lev * 4 + 3] = ys - Y0;
    }
    __syncthreads();

    // 16 px * 300 unique taps, each a 128-long dot product
    for (int tt = tid; tt < 16 * 300; tt += 256) {
        int p = tt / 300;
        int t = tt - p * 300;
        int lev = (t < 100) ? 0 : ((t < 200) ? 1 : 2);
        int tl = t - lev * 100;
        int r = tl / 10, cc = tl - 10 * r;
        int X0 = (int)sLev[p * 12 + lev * 4 + 0];
        int Y0 = (int)sLev[p * 12 + lev * 4 + 1];
        int WL = WID >> lev, HL = HEI >> lev;
        int y = Y0 - 4 + r, x = X0 - 4 + cc;
        float g = 0.f;
        if ((unsigned)x < (unsigned)WL && (unsigned)y < (unsigned)HL) {
            size_t base = (lev == 0) ? OF2L0 : ((lev == 1) ? OF2L1 : OF2L2);
            const float4* col = (const float4*)(ws + base + ((size_t)(b * HL * WL + y * WL + x)) * 128);
            const float4* av = (const float4*)(sf1 + p * 128);
            float a0 = 0, a1 = 0, a2 = 0, a3 = 0;
            #pragma unroll
            for (int q = 0; q < 32; q++) {
                float4 bv = col[q];
                float4 fv = av[q];
                a0 += fv.x * bv.x; a1 += fv.y * bv.y;
                a2 += fv.z * bv.z; a3 += fv.w * bv.w;
            }
            g = ((a0 + a1) + (a2 + a3)) * 0.08838834764831845f;   // 1/sqrt(128)
        }
        sG[p * 300 + t] = g;
    }
    __syncthreads();

    // 243 features per pixel; k-major / p-minor so channel-first writes are 16-float segments
    for (int idx = tid; idx < 16 * IC; idx += 256) {
        int k = idx >> 4, p = idx & 15;
        int lev = (k < 81) ? 0 : ((k < 162) ? 1 : 2);
        int kk = k - lev * 81;
        int dyi = kk / 9, dxi = kk - 9 * dyi;
        float fx = sLev[p * 12 + lev * 4 + 2];
        float fy = sLev[p * 12 + lev * 4 + 3];
        const float* Gp = sG + p * 300 + lev * 100 + dyi * 10 + dxi;
        float v = (1.f - fy) * ((1.f - fx) * Gp[0] + fx * Gp[1])
                +        fy  * ((1.f - fx) * Gp[10] + fx * Gp[11]);
        ws[OFEAT + ((size_t)(b * IC + k)) * HW + pb0 + p] = v;
    }
}

__launch_bounds__(256)
__global__ void k_conv(const float* __restrict__ cb, float* __restrict__ ws) {
    const int tid = threadIdx.x;
    const int pix0 = blockIdx.x * 16;
    const int b = pix0 / HW;
    const int pb0 = pix0 - b * HW;
    const int o = tid & 127;
    const int half = __builtin_amdgcn_readfirstlane(tid >> 7);   // wave-uniform

    const float* fbase = ws + OFEAT + ((size_t)b * IC) * HW + pb0 + half * 8;
    const float* wt = ws + OWT;
    float acc[8] = {0, 0, 0, 0, 0, 0, 0, 0};
    for (int k = 0; k < IC; ++k) {
        float wv = wt[k * 128 + o];
        const float4* fp = (const float4*)(fbase + (size_t)k * HW);
        float4 f0 = fp[0], f1 = fp[1];
        acc[0] += f0.x * wv; acc[1] += f0.y * wv; acc[2] += f0.z * wv; acc[3] += f0.w * wv;
        acc[4] += f1.x * wv; acc[5] += f1.y * wv; acc[6] += f1.z * wv; acc[7] += f1.w * wv;
    }
    float bias = cb[o];
    float* yp = ws + OYPRE + ((size_t)pix0 + half * 8) * 128 + o;
    #pragma unroll
    for (int p = 0; p < 8; ++p) yp[(size_t)p * 128] = acc[p] + bias;
}

__global__ void k_gnstats(float* __restrict__ ws) {
    const int bg = blockIdx.x;              // 0..15 = b*8+g
    const int b = bg >> 3, g = bg & 7;
    const int tid = threadIdx.x;
    const float* yp = ws + OYPRE + (size_t)b * HW * 128 + g * 16;
    float s = 0.f, s2 = 0.f;
    for (int idx = tid; idx < HW * 16; idx += 256) {
        int pix = idx >> 4, cl = idx & 15;
        float v = yp[(size_t)pix * 128 + cl];
        s += v; s2 += v * v;
    }
    __shared__ float rs[256], rs2[256];
    rs[tid] = s; rs2[tid] = s2;
    __syncthreads();
    for (int st = 128; st > 0; st >>= 1) {
        if (tid < st) { rs[tid] += rs[tid + st]; rs2[tid] += rs2[tid + st]; }
        __syncthreads();
    }
    if (tid == 0) {
        const float invN = 1.f / (float)(HW * 16);
        float mean = rs[0] * invN;
        float var = rs2[0] * invN - mean * mean;
        ws[OSTAT + bg * 2] = mean;
        ws[OSTAT + bg * 2 + 1] = rsqrtf(var + 1e-5f);
    }
}

__global__ void k_finish(const float* __restrict__ gw, const float* __restrict__ gb,
                         const float* __restrict__ ws, float* __restrict__ out) {
    int tid = blockIdx.x * 256 + threadIdx.x;   // layout [b][c][pix], pix fastest
    int pix = tid % HW;
    int c = (tid / HW) & 127;
    int b = tid / (HW * 128);
    int g = c >> 4;
    float mean = ws[OSTAT + (b * 8 + g) * 2];
    float rstd = ws[OSTAT + (b * 8 + g) * 2 + 1];
    float v = ws[OYPRE + ((size_t)(b * HW + pix)) * 128 + c];
    v = (v - mean) * rstd * gw[c] + gb[c];
    out[tid] = v > 0.f ? v : 0.1f * v;
}

extern "C" void kernel_launch(void* const* d_in, const int* in_sizes, int n_in,
                              void* d_out, int out_size, void* d_ws, size_t ws_size,
                              hipStream_t stream) {
    const float* f1  = (const float*)d_in[0];
    const float* f2  = (const float*)d_in[1];
    const float* txy = (const float*)d_in[2];
    const float* cw  = (const float*)d_in[3];
    const float* cb  = (const float*)d_in[4];
    const float* gw  = (const float*)d_in[5];
    const float* gb  = (const float*)d_in[6];
    float* ws  = (float*)d_ws;
    float* out = (float*)d_out;

    k_transpose<<<dim3(6144, 2), 256, 0, stream>>>(f1, f2, ws);
    k_wt<<<122, 256, 0, stream>>>(cw, ws);
    k_pool<<<1536, 256, 0, stream>>>(ws + OF2L0, ws + OF2L1, 32, 48);
    k_pool<<<384, 256, 0, stream>>>(ws + OF2L1, ws + OF2L2, 16, 24);
    k_corr<<<768, 256, 0, stream>>>(txy, ws);
    k_conv<<<768, 256, 0, stream>>>(cb, ws);
    k_gnstats<<<16, 256, 0, stream>>>(ws);
    k_finish<<<6144, 256, 0, stream>>>(gw, gb, ws, out);
}

// Round 4
// 277.944 us; speedup vs baseline: 1.4185x; 1.4185x over previous
//
#include <hip/hip_runtime.h>

#define HW   6144
#define WID  96
#define HEI  64
#define CH   128
#define IC   243
#define OC   128

// ws float offsets (layout kept from round 0; OFEAT region now unused)
#define OF1T   0u
#define OF2L0  1572864u
#define OF2L1  3145728u
#define OF2L2  3538944u
#define OWT    3637248u
#define OFEAT  3668352u
#define OYPRE  6654336u
#define OSTAT  8227200u

__global__ void k_transpose(const float* __restrict__ f1, const float* __restrict__ f2,
                            float* __restrict__ ws) {
    int tid = blockIdx.x * 256 + threadIdx.x;           // 0..1572863
    const float* src = blockIdx.y ? f2 : f1;
    float* dst = ws + (blockIdx.y ? OF2L0 : OF1T);
    int c = tid & 127;
    int rest = tid >> 7;          // b*HW + pix
    int b = rest / HW;
    int pix = rest - b * HW;
    dst[tid] = src[((size_t)(b * CH + c)) * HW + pix];
}

__global__ void k_wt(const float* __restrict__ w, float* __restrict__ ws) {
    int tid = blockIdx.x * 256 + threadIdx.x;
    if (tid < IC * OC) {
        int k = tid >> 7, o = tid & 127;
        ws[OWT + tid] = w[o * IC + k];
    }
}

__global__ void k_pool(const float* __restrict__ src, float* __restrict__ dst, int Ho, int Wo) {
    int tid = blockIdx.x * 256 + threadIdx.x;
    int c = tid & 127;
    int rest = tid >> 7;
    int x = rest % Wo; rest /= Wo;
    int y = rest % Ho;
    int b = rest / Ho;
    int Wi = Wo * 2;
    const float* s = src + ((size_t)((b * (Ho * 2) + 2 * y) * Wi + 2 * x)) * CH + c;
    float v = s[0] + s[CH] + s[(size_t)Wi * CH] + s[(size_t)Wi * CH + CH];
    dst[tid] = 0.25f * v;
}

// Fused: correlation taps (cooperative, coalesced) + bilinear + 1x1 conv.
// Block = 256 thr (4 waves) handles 16 pixels.
// Tap phase: 16-lane group per pixel; lane l owns channels [l*4..l*4+3] and [64+l*4..+3].
__launch_bounds__(256)
__global__ void k_corr_conv(const float* __restrict__ txy, const float* __restrict__ cb,
                            float* __restrict__ ws) {
    const int tid = threadIdx.x;
    const int pix0 = blockIdx.x * 16;
    const int b = pix0 / HW;
    const int pb0 = pix0 - b * HW;

    __shared__ float sG[16 * 300];     // unique-tap dot products, [p][lev*100 + r*10 + c]
    __shared__ float sF[IC * 16];      // features, [k][p]
    __shared__ float sLev[16 * 12];    // per pixel/level: X0, Y0, fx, fy

    if (tid < 48) {
        int p = tid / 3, lev = tid - 3 * p;
        float tx = txy[(b * 2 + 0) * HW + pb0 + p];
        float ty = txy[(b * 2 + 1) * HW + pb0 + p];
        float inv = (lev == 0) ? 1.f : ((lev == 1) ? 0.5f : 0.25f);
        float xs = tx * inv, ys = ty * inv;
        float X0 = floorf(xs), Y0 = floorf(ys);
        sLev[p * 12 + lev * 4 + 0] = X0;
        sLev[p * 12 + lev * 4 + 1] = Y0;
        sLev[p * 12 + lev * 4 + 2] = xs - X0;
        sLev[p * 12 + lev * 4 + 3] = ys - Y0;
    }

    // f1 fragment in registers (coalesced: 16 lanes x 16B contiguous, x2)
    const int lane = tid & 63;
    const int g = lane >> 4;           // pixel-in-wave
    const int l = lane & 15;           // channel chunk
    const int p = (tid >> 6) * 4 + g;  // pixel-in-block
    const float* f1p = ws + OF1T + ((size_t)(pix0 + p)) * 128;
    const float4 f1a = *(const float4*)(f1p + l * 4);
    const float4 f1b = *(const float4*)(f1p + 64 + l * 4);

    __syncthreads();

    const float scale = 0.08838834764831845f;   // 1/sqrt(128)
    #pragma unroll
    for (int lev = 0; lev < 3; ++lev) {
        const int WL = WID >> lev, HL = HEI >> lev;
        const size_t baseoff = (lev == 0) ? OF2L0 : ((lev == 1) ? OF2L1 : OF2L2);
        const float* base = ws + baseoff + (size_t)b * HL * WL * 128;
        const int X0 = (int)sLev[p * 12 + lev * 4 + 0];
        const int Y0 = (int)sLev[p * 12 + lev * 4 + 1];
        float* sGp = sG + p * 300 + lev * 100;
        for (int r = 0; r < 10; ++r) {
            int y = Y0 - 4 + r;
            bool yok = (unsigned)y < (unsigned)HL;
            int yc = min(max(y, 0), HL - 1);
            const float* rowp = base + (size_t)(yc * WL) * 128;
            #pragma unroll
            for (int c4 = 0; c4 < 10; ++c4) {
                int x = X0 - 4 + c4;
                bool ok = yok && ((unsigned)x < (unsigned)WL);
                int xc = min(max(x, 0), WL - 1);
                const float* colp = rowp + xc * 128;
                float4 bva = *(const float4*)(colp + l * 4);
                float4 bvb = *(const float4*)(colp + 64 + l * 4);
                float d = f1a.x * bva.x + f1a.y * bva.y + f1a.z * bva.z + f1a.w * bva.w
                        + f1b.x * bvb.x + f1b.y * bvb.y + f1b.z * bvb.z + f1b.w * bvb.w;
                d += __shfl_xor(d, 1);
                d += __shfl_xor(d, 2);
                d += __shfl_xor(d, 4);
                d += __shfl_xor(d, 8);
                if (l == 0) sGp[r * 10 + c4] = ok ? d * scale : 0.f;
            }
        }
    }
    __syncthreads();

    // bilinear combine -> features in LDS
    for (int idx = tid; idx < 16 * IC; idx += 256) {
        int k = idx >> 4, p2 = idx & 15;
        int lev = (k < 81) ? 0 : ((k < 162) ? 1 : 2);
        int kk = k - lev * 81;
        int dyi = kk / 9, dxi = kk - 9 * dyi;
        float fx = sLev[p2 * 12 + lev * 4 + 2];
        float fy = sLev[p2 * 12 + lev * 4 + 3];
        const float* Gp = sG + p2 * 300 + lev * 100 + dyi * 10 + dxi;
        float v = (1.f - fy) * ((1.f - fx) * Gp[0] + fx * Gp[1])
                +        fy  * ((1.f - fx) * Gp[10] + fx * Gp[11]);
        sF[k * 16 + p2] = v;
    }
    __syncthreads();

    // 1x1 conv from LDS (sF reads are wave-uniform broadcasts)
    const int o = tid & 127;
    const int ph = tid >> 7;     // 0..1 -> pixels ph*8 .. ph*8+7
    float acc[8] = {0, 0, 0, 0, 0, 0, 0, 0};
    const float* wt = ws + OWT;
    for (int k = 0; k < IC; ++k) {
        float wv = wt[k * 128 + o];
        const float4* fp = (const float4*)(sF + k * 16 + ph * 8);
        float4 f0 = fp[0], f1v = fp[1];
        acc[0] += f0.x * wv;  acc[1] += f0.y * wv;  acc[2] += f0.z * wv;  acc[3] += f0.w * wv;
        acc[4] += f1v.x * wv; acc[5] += f1v.y * wv; acc[6] += f1v.z * wv; acc[7] += f1v.w * wv;
    }
    float bias = cb[o];
    float* yp = ws + OYPRE + ((size_t)pix0 + ph * 8) * 128 + o;
    #pragma unroll
    for (int pp = 0; pp < 8; ++pp) yp[(size_t)pp * 128] = acc[pp] + bias;
}

__global__ void k_gnstats(float* __restrict__ ws) {
    const int bg = blockIdx.x;              // 0..15 = b*8+g
    const int b = bg >> 3, g = bg & 7;
    const int tid = threadIdx.x;
    const float* yp = ws + OYPRE + (size_t)b * HW * 128 + g * 16;
    float s = 0.f, s2 = 0.f;
    for (int idx = tid; idx < HW * 16; idx += 256) {
        int pix = idx >> 4, cl = idx & 15;
        float v = yp[(size_t)pix * 128 + cl];
        s += v; s2 += v * v;
    }
    __shared__ float rs[256], rs2[256];
    rs[tid] = s; rs2[tid] = s2;
    __syncthreads();
    for (int st = 128; st > 0; st >>= 1) {
        if (tid < st) { rs[tid] += rs[tid + st]; rs2[tid] += rs2[tid + st]; }
        __syncthreads();
    }
    if (tid == 0) {
        const float invN = 1.f / (float)(HW * 16);
        float mean = rs[0] * invN;
        float var = rs2[0] * invN - mean * mean;
        ws[OSTAT + bg * 2] = mean;
        ws[OSTAT + bg * 2 + 1] = rsqrtf(var + 1e-5f);
    }
}

__global__ void k_finish(const float* __restrict__ gw, const float* __restrict__ gb,
                         const float* __restrict__ ws, float* __restrict__ out) {
    int tid = blockIdx.x * 256 + threadIdx.x;   // layout [b][c][pix], pix fastest
    int pix = tid % HW;
    int c = (tid / HW) & 127;
    int b = tid / (HW * 128);
    int g = c >> 4;
    float mean = ws[OSTAT + (b * 8 + g) * 2];
    float rstd = ws[OSTAT + (b * 8 + g) * 2 + 1];
    float v = ws[OYPRE + ((size_t)(b * HW + pix)) * 128 + c];
    v = (v - mean) * rstd * gw[c] + gb[c];
    out[tid] = v > 0.f ? v : 0.1f * v;
}

extern "C" void kernel_launch(void* const* d_in, const int* in_sizes, int n_in,
                              void* d_out, int out_size, void* d_ws, size_t ws_size,
                              hipStream_t stream) {
    const float* f1  = (const float*)d_in[0];
    const float* f2  = (const float*)d_in[1];
    const float* txy = (const float*)d_in[2];
    const float* cw  = (const float*)d_in[3];
    const float* cb  = (const float*)d_in[4];
    const float* gw  = (const float*)d_in[5];
    const float* gb  = (const float*)d_in[6];
    float* ws  = (float*)d_ws;
    float* out = (float*)d_out;

    k_transpose<<<dim3(6144, 2), 256, 0, stream>>>(f1, f2, ws);
    k_wt<<<122, 256, 0, stream>>>(cw, ws);
    k_pool<<<1536, 256, 0, stream>>>(ws + OF2L0, ws + OF2L1, 32, 48);
    k_pool<<<384, 256, 0, stream>>>(ws + OF2L1, ws + OF2L2, 16, 24);
    k_corr_conv<<<768, 256, 0, stream>>>(txy, cb, ws);
    k_gnstats<<<16, 256, 0, stream>>>(ws);
    k_finish<<<6144, 256, 0, stream>>>(gw, gb, ws, out);
}

// Round 5
// 113.367 us; speedup vs baseline: 3.4778x; 2.4517x over previous
//
#include <hip/hip_runtime.h>

#define HW   6144
#define WID  96
#define HEI  64
#define CH   128
#define IC   243

// half-region offsets (in _Float16 units from ws base)
#define HF1   0u
#define HL0   1572864u
#define HL1   3145728u
#define HL2   3538944u
// float-region offsets (in float units from ws base); half region ends at float idx 1818624
#define FWT   1818624u
#define FYP   1849728u
#define FST   3422592u
#define FST2  3422848u

typedef _Float16 v2h __attribute__((ext_vector_type(2)));
typedef _Float16 h8  __attribute__((ext_vector_type(8)));

#if __has_builtin(__builtin_amdgcn_fdot2)
#define FDOT2(a,b,c) __builtin_amdgcn_fdot2((a),(b),(c),false)
#else
static __device__ __forceinline__ float fdot2_fb(v2h a, v2h b, float c){
    return c + (float)a[0]*(float)b[0] + (float)a[1]*(float)b[1];
}
#define FDOT2(a,b,c) fdot2_fb((a),(b),(c))
#endif

static __device__ __forceinline__ v2h g2(h8 v, int i){ v2h r; r[0]=v[2*i]; r[1]=v[2*i+1]; return r; }

// LDS-tiled transpose [B,C,HW] f32 -> [pix][ch] fp16. grid (192, 4, 2)
__global__ void k_t(const float* __restrict__ f1, const float* __restrict__ f2,
                    float* __restrict__ ws) {
    _Float16* wh = (_Float16*)ws;
    const float* src = blockIdx.z ? f2 : f1;
    _Float16* dst = wh + (blockIdx.z ? HL0 : HF1);
    const int t = threadIdx.x;
    const int pix0 = blockIdx.x * 64;
    const int c0 = blockIdx.y * 32;
    const int b = pix0 / HW;
    const int pb = pix0 - b * HW;
    __shared__ float sT[32][65];
    const int px = t & 63;
    const int cb8 = (t >> 6) * 8;
    #pragma unroll
    for (int i = 0; i < 8; i++)
        sT[cb8 + i][px] = src[((size_t)(b * 128 + c0 + cb8 + i)) * HW + pb + px];
    __syncthreads();
    const int pw = t >> 2;
    const int cg = (t & 3) * 8;
    h8 hv;
    #pragma unroll
    for (int i = 0; i < 8; i++) hv[i] = (_Float16)sT[cg + i][pw];
    *(h8*)(dst + ((size_t)(pix0 + pw)) * 128 + c0 + cg) = hv;
}

__global__ void k_wt(const float* __restrict__ w, float* __restrict__ ws) {
    int tid = blockIdx.x * 256 + threadIdx.x;
    if (tid < IC * 128) {
        int k = tid >> 7, o = tid & 127;
        ws[FWT + tid] = w[o * IC + k];
    }
}

// fp16 2x2 avg-pool, channel-last. out elems = npix_out*128, 8 per thread
__global__ void k_pool(const _Float16* __restrict__ src, _Float16* __restrict__ dst,
                       int Ho, int Wo) {
    int gt = blockIdx.x * 256 + threadIdx.x;
    int oc = gt & 15;
    int rest = gt >> 4;
    int x = rest % Wo; rest /= Wo;
    int y = rest % Ho; int b = rest / Ho;
    int Wi = Wo * 2;
    const _Float16* s = src + ((size_t)((b * (Ho * 2) + 2 * y) * Wi + 2 * x)) * 128 + oc * 8;
    h8 a  = *(const h8*)s;
    h8 bb = *(const h8*)(s + 128);
    h8 c  = *(const h8*)(s + (size_t)Wi * 128);
    h8 d  = *(const h8*)(s + (size_t)Wi * 128 + 128);
    h8 r;
    #pragma unroll
    for (int j = 0; j < 8; j++)
        r[j] = (_Float16)(0.25f * ((float)a[j] + (float)bb[j] + (float)c[j] + (float)d[j]));
    *(h8*)(dst + (size_t)gt * 8) = r;
}

// Fused corr taps + bilinear + 1x1 conv. 256 thr, 8 px/block.
// 16 lanes per group; 2 groups per pixel (halves of the 10-row window).
__launch_bounds__(256)
__global__ void k_corr_conv(const float* __restrict__ txy, const float* __restrict__ cb,
                            float* __restrict__ ws) {
    const _Float16* wh = (const _Float16*)ws;
    const int tid = threadIdx.x;
    const int pix0 = blockIdx.x * 8;
    const int b = pix0 / HW;
    const int pb0 = pix0 - b * HW;

    __shared__ float sG[8 * 300];
    __shared__ float sF[IC * 8];
    __shared__ float sLev[8 * 12];

    if (tid < 24) {
        int p = tid / 3, lev = tid - 3 * p;
        float tx = txy[(b * 2 + 0) * HW + pb0 + p];
        float ty = txy[(b * 2 + 1) * HW + pb0 + p];
        float inv = (lev == 0) ? 1.f : ((lev == 1) ? 0.5f : 0.25f);
        float xs = tx * inv, ys = ty * inv;
        float X0 = floorf(xs), Y0 = floorf(ys);
        sLev[p * 12 + lev * 4 + 0] = X0;
        sLev[p * 12 + lev * 4 + 1] = Y0;
        sLev[p * 12 + lev * 4 + 2] = xs - X0;
        sLev[p * 12 + lev * 4 + 3] = ys - Y0;
    }

    const int l = tid & 15;
    const int grp = tid >> 4;          // 0..15
    const int p = grp >> 1;            // pixel 0..7
    const int half = grp & 1;          // row-half of window
    h8 av = *(const h8*)(wh + HF1 + ((size_t)(pix0 + p)) * 128 + l * 8);

    __syncthreads();

    const float scale = 0.08838834764831845f;   // 1/sqrt(128)
    #pragma unroll
    for (int lev = 0; lev < 3; ++lev) {
        const int WL = WID >> lev, HL = HEI >> lev;
        const _Float16* f2b = wh + ((lev == 0) ? HL0 : ((lev == 1) ? HL1 : HL2))
                              + (size_t)b * HL * WL * 128;
        const int X0 = (int)sLev[p * 12 + lev * 4 + 0];
        const int Y0 = (int)sLev[p * 12 + lev * 4 + 1];
        float* sGp = sG + p * 300 + lev * 100;
        for (int r = 0; r < 5; ++r) {
            int rr = half * 5 + r;
            int y = Y0 - 4 + rr;
            bool yok = (unsigned)y < (unsigned)HL;
            int yc = min(max(y, 0), HL - 1);
            const _Float16* rowp = f2b + (size_t)(yc * WL) * 128;
            #pragma unroll
            for (int c4 = 0; c4 < 10; ++c4) {
                int x = X0 - 4 + c4;
                bool ok = yok && ((unsigned)x < (unsigned)WL);
                int xc = min(max(x, 0), WL - 1);
                h8 bv = *(const h8*)(rowp + xc * 128 + l * 8);
                float d = FDOT2(g2(av, 0), g2(bv, 0), 0.f);
                d = FDOT2(g2(av, 1), g2(bv, 1), d);
                d = FDOT2(g2(av, 2), g2(bv, 2), d);
                d = FDOT2(g2(av, 3), g2(bv, 3), d);
                d += __shfl_xor(d, 1);
                d += __shfl_xor(d, 2);
                d += __shfl_xor(d, 4);
                d += __shfl_xor(d, 8);
                if (l == 0) sGp[rr * 10 + c4] = ok ? d * scale : 0.f;
            }
        }
    }
    __syncthreads();

    // bilinear combine -> features [k][p] in LDS
    for (int idx = tid; idx < 8 * IC; idx += 256) {
        int k = idx >> 3, p2 = idx & 7;
        int lev = (k < 81) ? 0 : ((k < 162) ? 1 : 2);
        int kk = k - lev * 81;
        int dyi = kk / 9, dxi = kk - 9 * dyi;
        float fx = sLev[p2 * 12 + lev * 4 + 2];
        float fy = sLev[p2 * 12 + lev * 4 + 3];
        const float* Gp = sG + p2 * 300 + lev * 100 + dyi * 10 + dxi;
        float v = (1.f - fy) * ((1.f - fx) * Gp[0] + fx * Gp[1])
                +        fy  * ((1.f - fx) * Gp[10] + fx * Gp[11]);
        sF[k * 8 + p2] = v;
    }
    __syncthreads();

    // 1x1 conv from LDS (broadcast reads)
    const int o = tid & 127;
    const int ph = tid >> 7;   // pixels ph*4 .. ph*4+3
    float a0 = 0, a1 = 0, a2 = 0, a3 = 0;
    const float* wt = ws + FWT;
    for (int k = 0; k < IC; ++k) {
        float wv = wt[k * 128 + o];
        float4 fv = *(const float4*)(sF + k * 8 + ph * 4);
        a0 += fv.x * wv; a1 += fv.y * wv; a2 += fv.z * wv; a3 += fv.w * wv;
    }
    float bias = cb[o];
    float* yp = ws + FYP + ((size_t)(pix0 + ph * 4)) * 128 + o;
    yp[0] = a0 + bias; yp[128] = a1 + bias; yp[256] = a2 + bias; yp[384] = a3 + bias;
}

__global__ void k_gnpart(float* __restrict__ ws) {
    const int s = blockIdx.x;     // slice 0..7
    const int bg = blockIdx.y;    // 0..15
    const int b = bg >> 3, g = bg & 7;
    const int tid = threadIdx.x;
    const float* yp = ws + FYP + (size_t)b * HW * 128 + g * 16;
    float sum = 0.f, sum2 = 0.f;
    for (int idx = tid; idx < 768 * 16; idx += 256) {
        int pix = s * 768 + (idx >> 4);
        float v = yp[(size_t)pix * 128 + (idx & 15)];
        sum += v; sum2 += v * v;
    }
    __shared__ float rs[256], rs2[256];
    rs[tid] = sum; rs2[tid] = sum2;
    __syncthreads();
    for (int st = 128; st > 0; st >>= 1) {
        if (tid < st) { rs[tid] += rs[tid + st]; rs2[tid] += rs2[tid + st]; }
        __syncthreads();
    }
    if (tid == 0) {
        ws[FST + (bg * 8 + s) * 2]     = rs[0];
        ws[FST + (bg * 8 + s) * 2 + 1] = rs2[0];
    }
}

__global__ void k_gnfinal(float* __restrict__ ws) {
    int t = threadIdx.x;
    if (t < 16) {
        float s = 0.f, s2 = 0.f;
        for (int i = 0; i < 8; i++) {
            s  += ws[FST + (t * 8 + i) * 2];
            s2 += ws[FST + (t * 8 + i) * 2 + 1];
        }
        const float invN = 1.f / (float)(HW * 16);
        float mean = s * invN;
        float var = s2 * invN - mean * mean;
        ws[FST2 + t * 2]     = mean;
        ws[FST2 + t * 2 + 1] = rsqrtf(var + 1e-5f);
    }
}

__global__ void k_finish(const float* __restrict__ gw, const float* __restrict__ gb,
                         const float* __restrict__ ws, float* __restrict__ out) {
    int tid = blockIdx.x * 256 + threadIdx.x;   // [b][c][pix], pix fastest
    int pix = tid % HW;
    int c = (tid / HW) & 127;
    int b = tid / (HW * 128);
    int g = c >> 4;
    float mean = ws[FST2 + (b * 8 + g) * 2];
    float rstd = ws[FST2 + (b * 8 + g) * 2 + 1];
    float v = ws[FYP + ((size_t)(b * HW + pix)) * 128 + c];
    v = (v - mean) * rstd * gw[c] + gb[c];
    out[tid] = v > 0.f ? v : 0.1f * v;
}

extern "C" void kernel_launch(void* const* d_in, const int* in_sizes, int n_in,
                              void* d_out, int out_size, void* d_ws, size_t ws_size,
                              hipStream_t stream) {
    const float* f1  = (const float*)d_in[0];
    const float* f2  = (const float*)d_in[1];
    const float* txy = (const float*)d_in[2];
    const float* cw  = (const float*)d_in[3];
    const float* cb  = (const float*)d_in[4];
    const float* gw  = (const float*)d_in[5];
    const float* gb  = (const float*)d_in[6];
    float* ws = (float*)d_ws;
    _Float16* wh = (_Float16*)d_ws;
    float* out = (float*)d_out;

    k_t<<<dim3(192, 4, 2), 256, 0, stream>>>(f1, f2, ws);
    k_wt<<<122, 256, 0, stream>>>(cw, ws);
    k_pool<<<192, 256, 0, stream>>>(wh + HL0, wh + HL1, 32, 48);
    k_pool<<<48, 256, 0, stream>>>(wh + HL1, wh + HL2, 16, 24);
    k_corr_conv<<<1536, 256, 0, stream>>>(txy, cb, ws);
    k_gnpart<<<dim3(8, 16), 256, 0, stream>>>(ws);
    k_gnfinal<<<1, 64, 0, stream>>>(ws);
    k_finish<<<6144, 256, 0, stream>>>(gw, gb, ws, out);
}